// Round 1
// baseline (277.998 us; speedup 1.0000x reference)
//
#include <hip/hip_runtime.h>
#include <math.h>

typedef unsigned int u32;
typedef __attribute__((ext_vector_type(4))) unsigned int uint4v;

// out[r][c] = h[r][c] * S[c][c], S diagonal +-1 (fp32) => XOR of the fp32
// sign bit of S's diagonal into h.
//
// Single fused kernel (v2): the mask-precompute dispatch is removed.
// Fast path (stride % cpr == 0, full 8-chunk coverage): each thread owns a
// fixed 4-column group; it reads its 4 diagonal signs of S directly
// (S diagonal = 4096 cache lines ~ 256 KB unique -> L2-resident after the
// first touching blocks; the 4 load latencies hide under the 8 outstanding
// NT h-loads), then streams 8 x 16B chunks with non-temporal load/xor/store
// (MLP = 12: 8 h-loads + 4 S-loads in flight before the first wait).
// Slow path handles any leftover chunks / non-divisible strides.

__global__ __launch_bounds__(256) void parity_fused_kernel(
    const uint4v* __restrict__ hv,
    const u32*    __restrict__ S,
    uint4v*       __restrict__ ov,
    int dim, int cpr,                 // cpr = dim/4 chunks per row
    long long n_chunks)
{
    const long long tid = (long long)blockIdx.x * blockDim.x + threadIdx.x;
    const long long s   = (long long)gridDim.x * blockDim.x;
    const long long diag_stride = (long long)dim + 1;  // S[c][c] = S[c*(dim+1)]

    if ((s % cpr) == 0 && tid + 7 * s < n_chunks) {
        // Fixed column group for this thread across all 8 chunks.
        const long long c0 = (tid % cpr) * 4;
        uint4v m;
#pragma unroll
        for (int j = 0; j < 4; ++j)
            m[j] = S[(c0 + j) * diag_stride] & 0x80000000u;
        uint4v v[8];
#pragma unroll
        for (int k = 0; k < 8; ++k)
            v[k] = __builtin_nontemporal_load(&hv[tid + k * s]);
#pragma unroll
        for (int k = 0; k < 8; ++k) v[k] ^= m;
#pragma unroll
        for (int k = 0; k < 8; ++k)
            __builtin_nontemporal_store(v[k], &ov[tid + k * s]);
    } else {
        for (long long i = tid; i < n_chunks; i += s) {
            const long long c0 = (i % cpr) * 4;
            uint4v v = __builtin_nontemporal_load(&hv[i]);
#pragma unroll
            for (int j = 0; j < 4; ++j)
                v[j] ^= (S[(c0 + j) * diag_stride] & 0x80000000u);
            __builtin_nontemporal_store(v, &ov[i]);
        }
    }
    // Scalar tail for n not divisible by 4 (not hit at 8192x4096).
    if (tid == 0) {
        const u32* hs = (const u32*)hv;
        u32* os = (u32*)ov;
        const long long n_tail_start = n_chunks * 4;
        const long long n_total = n_tail_start + 0;  // tail handled by caller arg below
        (void)hs; (void)os; (void)n_total;
    }
}

// Tail kernel avoided: caller guarantees element count divisible by 4 or
// handles the remainder via the scalar kernel below.
__global__ __launch_bounds__(64) void parity_tail_kernel(
    const u32* __restrict__ h, const u32* __restrict__ S, u32* __restrict__ out,
    int dim, long long start, long long n)
{
    const long long i = start + threadIdx.x;
    if (i < n) {
        const long long c = i % dim;
        out[i] = h[i] ^ (S[c * (long long)(dim + 1)] & 0x80000000u);
    }
}

static int gcd_int(int a, int b) { while (b) { int t = a % b; a = b; b = t; } return a; }

extern "C" void kernel_launch(void* const* d_in, const int* in_sizes, int n_in,
                              void* d_out, int out_size, void* d_ws, size_t ws_size,
                              hipStream_t stream) {
    (void)n_in; (void)out_size; (void)d_ws; (void)ws_size;
    const u32* h = (const u32*)d_in[0];
    const u32* S = (const u32*)d_in[1];
    u32* out = (u32*)d_out;

    const long long s_elems = (long long)in_sizes[1];
    const int dim = (int)llroundl(sqrtl((long double)s_elems));  // 4096
    const long long n = (long long)in_sizes[0];
    const long long n_chunks = n >> 2;        // 4 fp32 per 16B chunk
    const int cpr = dim >> 2;                 // 1024

    const int block = 256;
    // grid such that (grid*block) % cpr == 0 (keeps each thread on a fixed
    // column group) and 8 chunks/thread cover n_chunks in one pass.
    // 8192x4096: grid = 4096, stride = 1,048,576 chunks, 8*stride == n_chunks.
    long long grid = (n_chunks + (long long)block * 8 - 1) / ((long long)block * 8);
    if (grid < 1) grid = 1;
    const int step = cpr / gcd_int(block, cpr);   // grid multiple making stride % cpr == 0
    if (step > 1) grid = ((grid + step - 1) / step) * step;

    parity_fused_kernel<<<(int)grid, block, 0, stream>>>(
        (const uint4v*)h, S, (uint4v*)out, dim, cpr, n_chunks);

    const long long tail = n - (n_chunks << 2);
    if (tail > 0) {
        parity_tail_kernel<<<1, 64, 0, stream>>>(h, S, out, dim, n_chunks << 2, n);
    }
}

// Round 2
// 267.714 us; speedup vs baseline: 1.0384x; 1.0384x over previous
//
#include <hip/hip_runtime.h>
#include <math.h>

typedef unsigned int u32;
typedef __attribute__((ext_vector_type(4))) unsigned int uint4v;

// out[r][c] = h[r][c] * S[c][c], S diagonal +-1 (fp32) => XOR of fp32 sign bit.
//
// v3: two-kernel structure (round-0 proven: apply < 79 us; round-1 fused
// scatter regressed to 86 us), with ALL non-temporal hints removed.
// Theory: NT load/store was the remaining 2x throttle vs the 6.3-6.7 TB/s
// plain-access ceiling demonstrated by fillBufferAligned and the m13 copy
// ubench. This kernel is now structurally identical to a grid-stride
// float4 copy + one coalesced 16B L2-hit mask load + XOR.

__global__ __launch_bounds__(256) void parity_mask_kernel(
    const u32* __restrict__ S, u32* __restrict__ mask, int dim)
{
    const int c = blockIdx.x * blockDim.x + threadIdx.x;
    if (c < dim) mask[c] = S[(long long)c * dim + c] & 0x80000000u;
}

__global__ __launch_bounds__(256) void parity_apply_kernel(
    const uint4v* __restrict__ hv,
    const uint4v* __restrict__ maskv,   // dim/4 sign-mask chunks (16 KB, L2-hit)
    uint4v* __restrict__ ov,
    int cpr,                            // chunks per row = dim/4
    long long n_chunks)
{
    const long long tid = (long long)blockIdx.x * blockDim.x + threadIdx.x;
    const long long s   = (long long)gridDim.x * blockDim.x;

    if ((s % cpr) == 0 && tid + 7 * s < n_chunks) {
        // Fixed column group for this thread across all 8 chunks:
        // one coalesced 16B mask load, then 8x {load, xor, store}.
        const uint4v m = maskv[(int)(tid % cpr)];
        uint4v v[8];
#pragma unroll
        for (int k = 0; k < 8; ++k)
            v[k] = hv[tid + k * s];          // plain cached load
#pragma unroll
        for (int k = 0; k < 8; ++k) v[k] ^= m;
#pragma unroll
        for (int k = 0; k < 8; ++k)
            ov[tid + k * s] = v[k];          // plain cached store
    } else {
        for (long long i = tid; i < n_chunks; i += s) {
            uint4v m = maskv[(int)(i % cpr)];
            uint4v v = hv[i];
            v ^= m;
            ov[i] = v;
        }
    }
}

// Fallback (ws too small): read S's diagonal directly.
__global__ __launch_bounds__(256) void parity_fallback_kernel(
    const u32* __restrict__ h, const u32* __restrict__ S, u32* __restrict__ out,
    int dim, long long n_chunks)
{
    const int cpr = dim >> 2;
    const long long tid    = (long long)blockIdx.x * blockDim.x + threadIdx.x;
    const long long stride = (long long)gridDim.x * blockDim.x;
    const uint4v* hv = (const uint4v*)h;
    uint4v* ov = (uint4v*)out;
    for (long long i = tid; i < n_chunks; i += stride) {
        const int c0 = (int)(i % cpr) * 4;
        uint4v v = hv[i];
#pragma unroll
        for (int j = 0; j < 4; ++j) {
            const long long c = c0 + j;
            v[j] ^= (S[c * (long long)dim + c] & 0x80000000u);
        }
        ov[i] = v;
    }
}

extern "C" void kernel_launch(void* const* d_in, const int* in_sizes, int n_in,
                              void* d_out, int out_size, void* d_ws, size_t ws_size,
                              hipStream_t stream) {
    (void)n_in; (void)out_size;
    const u32* h = (const u32*)d_in[0];
    const u32* S = (const u32*)d_in[1];
    u32* out = (u32*)d_out;

    const long long s_elems = (long long)in_sizes[1];
    const int dim = (int)llroundl(sqrtl((long double)s_elems));  // 4096
    const long long n = (long long)in_sizes[0];
    const long long n_chunks = n >> 2;        // 4 fp32 per 16B chunk
    const int cpr = dim >> 2;                 // 1024

    const int block = 256;
    if (ws_size >= (size_t)dim * sizeof(u32) && (dim & 3) == 0) {
        u32* mask = (u32*)d_ws;
        parity_mask_kernel<<<(dim + block - 1) / block, block, 0, stream>>>(
            S, mask, dim);
        // 8 chunks/thread: grid = ceil(n_chunks / (block*8)).
        // 8192x4096: 4096 blocks; stride = 1,048,576 = 1024*1024 -> fast path.
        long long grid = (n_chunks + (long long)block * 8 - 1) / ((long long)block * 8);
        if (grid < 1) grid = 1;
        parity_apply_kernel<<<(int)grid, block, 0, stream>>>(
            (const uint4v*)h, (const uint4v*)mask, (uint4v*)out, cpr, n_chunks);
    } else {
        int grid = 2048;
        if ((long long)grid * block > n_chunks) {
            grid = (int)((n_chunks + block - 1) / block);
            if (grid < 1) grid = 1;
        }
        parity_fallback_kernel<<<grid, block, 0, stream>>>(h, S, out, dim, n_chunks);
    }
}